// Round 15
// baseline (231.094 us; speedup 1.0000x reference)
//
#include <hip/hip_runtime.h>
#include <hip/hip_fp16.h>
#include <math.h>

#define DIMC 64
#define HIDC 32
#define IMH 512
#define IMW 512
#define TW 32
#define TH 16
#define HW 34
#define HH 18
#define NPIX (HW*HH)     // 612
#define NPIXP 624        // 39 chunks of 16
#define NCHUNK 39
#define VSTR 20          // v-buffer stride in words (16 used + 4 pad)
#define PLANE (IMH*IMW)
#define NTHR 768

// d_ws layout (u32 words)
#define IDOFF 0
#define W1OFF 16      // 2048 words: w1 as f16 [64][64]
#define W2OFF 2064    // 1024 words: w2 as f16 [64][32]
#define PWOFF 3088    // 288 words: packed (wdw[ch][k], wdw[ch+32][k]) f16 pairs, [9][32]

// swizzle: bits 1-3 of pixel index (bit 0 is degenerate across staging waves)
#define SWZ(p) ((((uint)(p) >> 1) & 7u) << 2)

typedef _Float16 half8  __attribute__((ext_vector_type(8)));
typedef __fp16   fp16x2 __attribute__((ext_vector_type(2)));
typedef float f32x4     __attribute__((ext_vector_type(4)));
typedef unsigned int uint;

union U4H8 { uint4 u; half8 h; };

static __device__ __forceinline__ uint pkrtz(float a, float b) {
    union { fp16x2 h; uint u; } x;
    x.h = __builtin_amdgcn_cvt_pkrtz(a, b);
    return x.u;
}
static __device__ __forceinline__ float lo16f(uint u) {
    union { uint u; _Float16 h[2]; } x; x.u = u; return (float)x.h[0];
}
static __device__ __forceinline__ float hi16f(uint u) {
    union { uint u; _Float16 h[2]; } x; x.u = u; return (float)x.h[1];
}
static __device__ __forceinline__ uint pkfma(uint w, uint t, uint acc) {
    union { uint u; __half2 h; } W, T, A;
    W.u = w; T.u = t; A.u = acc;
    A.h = __hfma2(W.h, T.h, A.h);
    return A.u;
}

// exact-enough GELU: erf via Abramowitz-Stegun 7.1.26 (|eps| < 1.5e-7), branchless
static __device__ __forceinline__ float gelu_f(float u) {
    const float z  = fabsf(u) * 0.70710678118654752f;
    const float t  = __builtin_amdgcn_rcpf(fmaf(0.3275911f, z, 1.0f));
    const float e  = __builtin_amdgcn_exp2f(-z * z * 1.4426950408889634f);
    float p = fmaf(t, 1.061405429f, -1.453152027f);
    p = fmaf(t, p, 1.421413741f);
    p = fmaf(t, p, -0.284496736f);
    p = fmaf(t, p, 0.254829592f);
    p = p * t;
    const float erf_abs = fmaf(-p, e, 1.0f);
    const float erfv = copysignf(erf_abs, u);
    return 0.5f * u * (1.0f + erfv);
}

// ---------------- prep: pack weights to f16 in d_ws, compute ident flag ----------------
__global__ __launch_bounds__(256)
void ffn_prep(const float* __restrict__ w1, const float* __restrict__ wdw,
              const float* __restrict__ w2, const float* __restrict__ wf,
              uint* __restrict__ ws)
{
    __shared__ int sid;
    const int tid = threadIdx.x;
    if (tid == 0) sid = 1;
    __syncthreads();
    bool ok = true;
    for (int i = tid; i < DIMC * 12; i += 256) ok = ok && (wf[i] == 1.0f);
    if (!ok) atomicAnd(&sid, 0);
    for (int i = tid; i < 2048; i += 256) ws[W1OFF + i] = pkrtz(w1[2*i], w1[2*i+1]);
    for (int i = tid; i < 1024; i += 256) ws[W2OFF + i] = pkrtz(w2[2*i], w2[2*i+1]);
    for (int i = tid; i < 288; i += 256) {
        const int k = i >> 5, ch = i & 31;
        ws[PWOFF + i] = pkrtz(wdw[ch*9 + k], wdw[(ch + HIDC)*9 + k]);
    }
    __syncthreads();
    if (tid == 0) ws[IDOFF] = (uint)sid;
}

// ---------------- main fused kernel: 768 threads, single-exposure staging ----------------
__global__ __launch_bounds__(NTHR, 6)
void ffn_main(const float* __restrict__ x,
              const uint*  __restrict__ ws,
              const float* __restrict__ wf,
              float* __restrict__ out)
{
    __shared__ uint ts[NPIXP * 32];   // 79872 B; swizzled halo/t, then v (stride 20) + fallback

    const int tid = threadIdx.x;
    // XCD-chunked bijective swizzle (2048 % 8 == 0)
    const int bid = ((blockIdx.x & 7) << 8) + (blockIdx.x >> 3);
    const int b  = bid >> 9;
    const int tr = bid & 511;
    const int ty = tr >> 4, tx = tr & 15;     // 32 tile-rows x 16 tile-cols
    const int oy = ty * TH, ox = tx * TW;

    const float* xb = x + (size_t)b * DIMC * PLANE;

    // ---------- Stage 0: x halo -> LDS f16 pairs, word = px*32 + (w ^ SWZ(px)) ----------
    // 720 tasks, ONE per thread (single latency exposure):
    //   quad T<576: T = cg*144 + r*8 + q (q fastest -> full-line coalescing), 4 px x 16 ch
    //   edge 576..719: 1 px (gx = ox-1 / ox+32, neighbor-core L2-hot) x 16 ch
    //   pad 720..731: zero px 612..623
    if (tid < 576) {
        const int cg = tid / 144;
        const int rm = tid - cg * 144;
        const int r  = rm >> 3;
        const int q  = rm & 7;
        const int gy = oy + r - 1;
        const int p0 = r * HW + 1 + 4 * q;
        if ((unsigned)gy >= IMH) {
            #pragma unroll
            for (int j = 0; j < 4; ++j) {
                const uint p = (uint)(p0 + j), base = p << 5, sw = SWZ(p);
                uint4 z = {0u, 0u, 0u, 0u};
                *reinterpret_cast<uint4*>(&ts[base + (((uint)(cg*8))   ^ sw)]) = z;
                *reinterpret_cast<uint4*>(&ts[base + (((uint)(cg*8+4)) ^ sw)]) = z;
            }
        } else {
            const float* xp = xb + (size_t)(cg*16) * PLANE + (size_t)gy * IMW + (ox + 4*q);
            f32x4 f[16];
            #pragma unroll
            for (int i = 0; i < 16; ++i)
                f[i] = *reinterpret_cast<const f32x4*>(xp + (size_t)i * PLANE);
            #pragma unroll
            for (int j = 0; j < 4; ++j) {
                const uint p = (uint)(p0 + j), base = p << 5, sw = SWZ(p);
                uint4 o0, o1;
                o0.x = pkrtz(f[0][j],  f[1][j]);  o0.y = pkrtz(f[2][j],  f[3][j]);
                o0.z = pkrtz(f[4][j],  f[5][j]);  o0.w = pkrtz(f[6][j],  f[7][j]);
                o1.x = pkrtz(f[8][j],  f[9][j]);  o1.y = pkrtz(f[10][j], f[11][j]);
                o1.z = pkrtz(f[12][j], f[13][j]); o1.w = pkrtz(f[14][j], f[15][j]);
                *reinterpret_cast<uint4*>(&ts[base + (((uint)(cg*8))   ^ sw)]) = o0;
                *reinterpret_cast<uint4*>(&ts[base + (((uint)(cg*8+4)) ^ sw)]) = o1;
            }
        }
    } else if (tid < 720) {
        const int E  = tid - 576;
        const int cg = E / 36;
        const int rm = E - cg * 36;
        const int s  = rm / 18;
        const int r  = rm - s * 18;
        const int gy = oy + r - 1;
        const int gx = s ? (ox + TW) : (ox - 1);
        const uint p = (uint)(r * HW + (s ? 33 : 0));
        const uint base = p << 5, sw = SWZ(p);
        if ((unsigned)gy >= IMH || (unsigned)gx >= IMW) {
            uint4 z = {0u, 0u, 0u, 0u};
            *reinterpret_cast<uint4*>(&ts[base + (((uint)(cg*8))   ^ sw)]) = z;
            *reinterpret_cast<uint4*>(&ts[base + (((uint)(cg*8+4)) ^ sw)]) = z;
        } else {
            const float* xp = xb + (size_t)(cg*16) * PLANE + (size_t)gy * IMW + gx;
            float f[16];
            #pragma unroll
            for (int i = 0; i < 16; ++i) f[i] = xp[(size_t)i * PLANE];
            uint4 o0, o1;
            o0.x = pkrtz(f[0], f[1]);   o0.y = pkrtz(f[2], f[3]);
            o0.z = pkrtz(f[4], f[5]);   o0.w = pkrtz(f[6], f[7]);
            o1.x = pkrtz(f[8], f[9]);   o1.y = pkrtz(f[10], f[11]);
            o1.z = pkrtz(f[12], f[13]); o1.w = pkrtz(f[14], f[15]);
            *reinterpret_cast<uint4*>(&ts[base + (((uint)(cg*8))   ^ sw)]) = o0;
            *reinterpret_cast<uint4*>(&ts[base + (((uint)(cg*8+4)) ^ sw)]) = o1;
        }
    } else if (tid < 732) {
        const uint p = (uint)(612 + tid - 720);
        const uint base = p << 5, sw = SWZ(p);
        uint4 z = {0u, 0u, 0u, 0u};
        #pragma unroll
        for (int g = 0; g < 8; ++g)
            *reinterpret_cast<uint4*>(&ts[base + (((uint)(g << 2)) ^ sw)]) = z;
    }

    const int lane = tid & 63, wid = tid >> 6;    // 12 waves
    const int l15 = lane & 15, lg = lane >> 4;

    // ---------- A-fragments from pre-converted f16 weights ----------
    half8 afrag1[4][2];
    const uint4* w1v = reinterpret_cast<const uint4*>(ws + W1OFF);
    #pragma unroll
    for (int mt = 0; mt < 4; ++mt)
        #pragma unroll
        for (int ks = 0; ks < 2; ++ks) {
            U4H8 u; u.u = w1v[(mt*16 + l15)*8 + ks*4 + lg];
            afrag1[mt][ks] = u.h;
        }
    half8 afrag2[4];
    const uint4* w2v = reinterpret_cast<const uint4*>(ws + W2OFF);
    #pragma unroll
    for (int mt = 0; mt < 4; ++mt) { U4H8 u; u.u = w2v[(mt*16 + l15)*4 + lg]; afrag2[mt] = u.h; }

    const uint ident = ws[IDOFF];
    __syncthreads();

    // ---------- Snapshot shortcut x in store-side layout (32 chunks over 12 waves) ----------
    uint xs[3][4][2];
    #pragma unroll
    for (int ci = 0; ci < 3; ++ci) {
        const int c = wid + ci*12;
        if (c < 32) {
            const int px = c*16 + l15;
            const int h  = ((px >> 5) + 1) * HW + (px & 31) + 1;
            const uint base = (uint)h << 5, sw = SWZ(h);
            #pragma unroll
            for (int mt = 0; mt < 4; ++mt) {
                const uint a = base + (((uint)(mt*8 + lg*2)) ^ sw);
                xs[ci][mt][0] = ts[a];
                xs[ci][mt][1] = ts[a + 1];
            }
        }
    }
    __syncthreads();

    // ---------- Stage A: t = W1 * x via MFMA f16, in-place (ch, ch+32) pairs ----------
    for (int chunk = wid; chunk < NCHUNK; chunk += 12) {
        const uint px = (uint)(chunk*16 + l15);
        const uint base = px << 5, sw = SWZ(px);
        f32x4 acc[4];
        #pragma unroll
        for (int mt = 0; mt < 4; ++mt) acc[mt] = (f32x4)0.0f;
        #pragma unroll
        for (int ks = 0; ks < 2; ++ks) {
            U4H8 u; u.u = *reinterpret_cast<const uint4*>(&ts[base + (((uint)(ks*16 + lg*4)) ^ sw)]);
            #pragma unroll
            for (int mt = 0; mt < 4; ++mt)
                acc[mt] = __builtin_amdgcn_mfma_f32_16x16x32_f16(afrag1[mt][ks], u.h, acc[mt], 0, 0, 0);
        }
        #pragma unroll
        for (int mt = 0; mt < 2; ++mt) {
            uint4 o;
            o.x = pkrtz(acc[mt][0], acc[mt+2][0]);
            o.y = pkrtz(acc[mt][1], acc[mt+2][1]);
            o.z = pkrtz(acc[mt][2], acc[mt+2][2]);
            o.w = pkrtz(acc[mt][3], acc[mt+2][3]);
            *reinterpret_cast<uint4*>(&ts[base + (((uint)(mt*16 + lg*4)) ^ sw)]) = o;
        }
    }
    __syncthreads();

    // ---------- Stage B: depthwise 3x3 via v_pk_fma_f16 (threads 0..511) ----------
    uint4 vo[4];
    if (tid < 512) {
        const int li = tid >> 5, lj = tid & 31;
        uint acc2[32];
        #pragma unroll
        for (int c = 0; c < 32; ++c) acc2[c] = 0u;
        #pragma unroll
        for (int k = 0; k < 9; ++k) {
            const int di = k / 3, dj = k - di * 3;
            const uint hpx = (uint)((li + di) * HW + (lj + dj));
            const uint base = hpx << 5, sw = SWZ(hpx);
            const uint4* pwv = reinterpret_cast<const uint4*>(ws + PWOFF + k*32);  // uniform -> s_load
            #pragma unroll
            for (int g = 0; g < 8; ++g) {
                const uint4 wv = pwv[g];
                const uint4 tv = *reinterpret_cast<const uint4*>(&ts[base + (((uint)(g << 2)) ^ sw)]);
                acc2[g*4+0] = pkfma(wv.x, tv.x, acc2[g*4+0]);
                acc2[g*4+1] = pkfma(wv.y, tv.y, acc2[g*4+1]);
                acc2[g*4+2] = pkfma(wv.z, tv.z, acc2[g*4+2]);
                acc2[g*4+3] = pkfma(wv.w, tv.w, acc2[g*4+3]);
            }
        }
        #pragma unroll
        for (int gg = 0; gg < 4; ++gg) {
            uint o[4];
            #pragma unroll
            for (int q = 0; q < 4; ++q) {
                const int c2 = gg*4 + q;
                const uint wa = acc2[2*c2], wb = acc2[2*c2 + 1];
                const float v0 = gelu_f(lo16f(wa)) * hi16f(wa);
                const float v1 = gelu_f(lo16f(wb)) * hi16f(wb);
                o[q] = pkrtz(v0, v1);
            }
            vo[gg].x = o[0]; vo[gg].y = o[1]; vo[gg].z = o[2]; vo[gg].w = o[3];
        }
    }
    __syncthreads();   // all t reads complete before v overwrites
    if (tid < 512) {
        const uint vb = (uint)tid * VSTR;
        #pragma unroll
        for (int gg = 0; gg < 4; ++gg)
            *reinterpret_cast<uint4*>(&ts[vb + (uint)(gg << 2)]) = vo[gg];
    }
    __syncthreads();

    // ---------- Stage D: y = W2 * v via MFMA; add f16 shortcut; store (32 chunks / 12 waves) ----------
    float* ob = out + (size_t)b * DIMC * PLANE;
    if (ident) {
        #pragma unroll
        for (int ci = 0; ci < 3; ++ci) {
            const int c = wid + ci*12;
            if (c < 32) {
                const uint px = (uint)(c*16 + l15);
                U4H8 u; u.u = *reinterpret_cast<const uint4*>(&ts[px * VSTR + (uint)(lg << 2)]);
                const size_t pix = (size_t)(oy + (int)(px >> 5)) * IMW + (ox + (int)(px & 31));
                float* op = ob + pix;
                #pragma unroll
                for (int mt = 0; mt < 4; ++mt) {
                    f32x4 a = __builtin_amdgcn_mfma_f32_16x16x32_f16(afrag2[mt], u.h, (f32x4)0.0f, 0, 0, 0);
                    #pragma unroll
                    for (int r = 0; r < 4; ++r) {
                        const int ch = mt*16 + lg*4 + r;
                        const uint xw = xs[ci][mt][r >> 1];
                        const float xv = (r & 1) ? hi16f(xw) : lo16f(xw);
                        op[(size_t)ch * PLANE] = a[r] + xv;
                    }
                }
            }
        }
    } else {
        // general path (not hit in bench): 4 passes of 16 channels; ys after v region
        float* ys = reinterpret_cast<float*>(ts + 10240);   // [16][520] floats = 8320 words
        for (int mt = 0; mt < 4; ++mt) {
            __syncthreads();
            #pragma unroll
            for (int ci = 0; ci < 3; ++ci) {
                const int c = wid + ci*12;
                if (c < 32) {
                    const uint px = (uint)(c*16 + l15);
                    U4H8 u; u.u = *reinterpret_cast<const uint4*>(&ts[px * VSTR + (uint)(lg << 2)]);
                    f32x4 a = __builtin_amdgcn_mfma_f32_16x16x32_f16(afrag2[mt], u.h, (f32x4)0.0f, 0, 0, 0);
                    #pragma unroll
                    for (int r = 0; r < 4; ++r)
                        ys[(lg*4 + r) * 520 + (int)px] = a[r];
                }
            }
            __syncthreads();
            if (tid < 512) {
                const int chl = tid >> 5;
                const int ch  = mt*16 + chl;
                const int pt  = tid & 31;
                const int pi = (pt >> 3) * 4, pj = (pt & 7) * 4;
                float yv[4][4];
                #pragma unroll
                for (int a = 0; a < 4; ++a)
                    #pragma unroll
                    for (int c = 0; c < 4; ++c)
                        yv[a][c] = ys[chl * 520 + (pi + a) * TW + (pj + c)];
                float Cr[4][4], Ci[4][4];
                #pragma unroll
                for (int j = 0; j < 4; ++j) {
                    const float s02 = yv[0][j] + yv[2][j], d02 = yv[0][j] - yv[2][j];
                    const float s13 = yv[1][j] + yv[3][j], d13 = yv[1][j] - yv[3][j];
                    Cr[0][j] = s02 + s13; Ci[0][j] = 0.0f;
                    Cr[1][j] = d02;       Ci[1][j] = -d13;
                    Cr[2][j] = s02 - s13; Ci[2][j] = 0.0f;
                    Cr[3][j] = d02;       Ci[3][j] = d13;
                }
                float Zr[4][3], Zi[4][3];
                #pragma unroll
                for (int u = 0; u < 4; ++u) {
                    const float r0 = Cr[u][0], r1 = Cr[u][1], r2 = Cr[u][2], r3 = Cr[u][3];
                    const float i0 = Ci[u][0], i1 = Ci[u][1], i2 = Ci[u][2], i3 = Ci[u][3];
                    Zr[u][0] = r0 + r1 + r2 + r3;     Zi[u][0] = i0 + i1 + i2 + i3;
                    Zr[u][1] = (r0 - r2) + (i1 - i3); Zi[u][1] = (i0 - i2) - (r1 - r3);
                    Zr[u][2] = r0 - r1 + r2 - r3;     Zi[u][2] = i0 - i1 + i2 - i3;
                    #pragma unroll
                    for (int vv = 0; vv < 3; ++vv) {
                        const float m = wf[ch * 12 + u * 3 + vv];
                        Zr[u][vv] *= m; Zi[u][vv] *= m;
                    }
                }
                float Ar[4][3], Ai[4][3];
                #pragma unroll
                for (int vv = 0; vv < 3; ++vv) {
                    const float r0 = Zr[0][vv], r1 = Zr[1][vv], r2 = Zr[2][vv], r3 = Zr[3][vv];
                    const float i0 = Zi[0][vv], i1 = Zi[1][vv], i2 = Zi[2][vv], i3 = Zi[3][vv];
                    Ar[0][vv] = r0 + r1 + r2 + r3;     Ai[0][vv] = i0 + i1 + i2 + i3;
                    Ar[1][vv] = (r0 - r2) - (i1 - i3); Ai[1][vv] = (i0 - i2) + (r1 - r3);
                    Ar[2][vv] = r0 - r1 + r2 - r3;     Ai[2][vv] = i0 - i1 + i2 - i3;
                    Ar[3][vv] = (r0 - r2) + (i1 - i3); Ai[3][vv] = (i0 - i2) - (r1 - r3);
                }
                const float* xc = xb + (size_t)ch * PLANE;
                float*       oc = ob + (size_t)ch * PLANE;
                #pragma unroll
                for (int a = 0; a < 4; ++a) {
                    const float A0 = Ar[a][0], A1r = Ar[a][1], A2 = Ar[a][2];
                    const float B1i = Ai[a][1];
                    float res[4];
                    res[0] = (A0 + 2.0f * A1r + A2) * 0.0625f;
                    res[1] = (A0 - 2.0f * B1i - A2) * 0.0625f;
                    res[2] = (A0 - 2.0f * A1r + A2) * 0.0625f;
                    res[3] = (A0 + 2.0f * B1i - A2) * 0.0625f;
                    #pragma unroll
                    for (int c = 0; c < 4; ++c) {
                        const size_t pix = (size_t)(oy + pi + a) * IMW + (ox + pj + c);
                        oc[pix] = res[c] + xc[pix];
                    }
                }
            }
        }
    }
}

extern "C" void kernel_launch(void* const* d_in, const int* in_sizes, int n_in,
                              void* d_out, int out_size, void* d_ws, size_t ws_size,
                              hipStream_t stream) {
    (void)in_sizes; (void)n_in; (void)ws_size; (void)out_size;
    const float* x   = (const float*)d_in[0];
    const float* w1  = (const float*)d_in[1];
    const float* wdw = (const float*)d_in[2];
    const float* w2  = (const float*)d_in[3];
    const float* wf  = (const float*)d_in[4];
    float* out = (float*)d_out;
    uint* ws = (uint*)d_ws;

    ffn_prep<<<1, 256, 0, stream>>>(w1, wdw, w2, wf, ws);
    const int blocks = 4 * (IMH / TH) * (IMW / TW);   // 2048
    ffn_main<<<blocks, NTHR, 0, stream>>>(x, ws, wf, out);
}

// Round 16
// 181.825 us; speedup vs baseline: 1.2710x; 1.2710x over previous
//
#include <hip/hip_runtime.h>
#include <hip/hip_fp16.h>
#include <math.h>

#define DIMC 64
#define HIDC 32
#define IMH 512
#define IMW 512
#define TW 32
#define TH 16
#define HW 34
#define HH 18
#define NPIX (HW*HH)     // 612
#define NPIXP 624        // 39 chunks of 16
#define NCHUNK 39
#define VSTR 20          // v-buffer stride in words (16 used + 4 pad)
#define PLANE (IMH*IMW)

// d_ws layout (u32 words)
#define IDOFF 0
#define W1OFF 16      // 2048 words: w1 as f16 [64][64]
#define W2OFF 2064    // 1024 words: w2 as f16 [64][32]
#define PWOFF 3088    // 288 words: packed (wdw[ch][k], wdw[ch+32][k]) f16 pairs, [9][32]

// swizzle on pixel bits 1-3 (bit 0 is parity-degenerate across staging waves)
#define SWZ(p) ((((uint)(p) >> 1) & 7u) << 2)

typedef _Float16 half8  __attribute__((ext_vector_type(8)));
typedef __fp16   fp16x2 __attribute__((ext_vector_type(2)));
typedef float f32x4     __attribute__((ext_vector_type(4)));
typedef unsigned int uint;

union U4H8 { uint4 u; half8 h; };

static __device__ __forceinline__ uint pkrtz(float a, float b) {
    union { fp16x2 h; uint u; } x;
    x.h = __builtin_amdgcn_cvt_pkrtz(a, b);
    return x.u;
}
static __device__ __forceinline__ float lo16f(uint u) {
    union { uint u; _Float16 h[2]; } x; x.u = u; return (float)x.h[0];
}
static __device__ __forceinline__ float hi16f(uint u) {
    union { uint u; _Float16 h[2]; } x; x.u = u; return (float)x.h[1];
}
static __device__ __forceinline__ uint pkfma(uint w, uint t, uint acc) {
    union { uint u; __half2 h; } W, T, A;
    W.u = w; T.u = t; A.u = acc;
    A.h = __hfma2(W.h, T.h, A.h);
    return A.u;
}

// exact-enough GELU: erf via Abramowitz-Stegun 7.1.26 (|eps| < 1.5e-7), branchless
static __device__ __forceinline__ float gelu_f(float u) {
    const float z  = fabsf(u) * 0.70710678118654752f;
    const float t  = __builtin_amdgcn_rcpf(fmaf(0.3275911f, z, 1.0f));
    const float e  = __builtin_amdgcn_exp2f(-z * z * 1.4426950408889634f);
    float p = fmaf(t, 1.061405429f, -1.453152027f);
    p = fmaf(t, p, 1.421413741f);
    p = fmaf(t, p, -0.284496736f);
    p = fmaf(t, p, 0.254829592f);
    p = p * t;
    const float erf_abs = fmaf(-p, e, 1.0f);
    const float erfv = copysignf(erf_abs, u);
    return 0.5f * u * (1.0f + erfv);
}

// ---------------- prep: pack weights to f16 in d_ws, compute ident flag ----------------
__global__ __launch_bounds__(256)
void ffn_prep(const float* __restrict__ w1, const float* __restrict__ wdw,
              const float* __restrict__ w2, const float* __restrict__ wf,
              uint* __restrict__ ws)
{
    __shared__ int sid;
    const int tid = threadIdx.x;
    if (tid == 0) sid = 1;
    __syncthreads();
    bool ok = true;
    for (int i = tid; i < DIMC * 12; i += 256) ok = ok && (wf[i] == 1.0f);
    if (!ok) atomicAnd(&sid, 0);
    for (int i = tid; i < 2048; i += 256) ws[W1OFF + i] = pkrtz(w1[2*i], w1[2*i+1]);
    for (int i = tid; i < 1024; i += 256) ws[W2OFF + i] = pkrtz(w2[2*i], w2[2*i+1]);
    for (int i = tid; i < 288; i += 256) {
        const int k = i >> 5, ch = i & 31;
        ws[PWOFF + i] = pkrtz(wdw[ch*9 + k], wdw[(ch + HIDC)*9 + k]);
    }
    __syncthreads();
    if (tid == 0) ws[IDOFF] = (uint)sid;
}

// ---------------- main fused kernel ----------------
__global__ __launch_bounds__(512, 4)
void ffn_main(const float* __restrict__ x,
              const uint*  __restrict__ ws,
              const float* __restrict__ wf,
              float* __restrict__ out)
{
    __shared__ uint ts[NPIXP * 32];   // 79872 B; swizzled halo/t, then v (stride 20) + fallback

    const int tid = threadIdx.x;
    // XCD-chunked bijective swizzle (2048 % 8 == 0)
    const int bid = ((blockIdx.x & 7) << 8) + (blockIdx.x >> 3);
    const int b  = bid >> 9;
    const int tr = bid & 511;
    const int ty = tr >> 4, tx = tr & 15;     // 32 tile-rows x 16 tile-cols
    const int oy = ty * TH, ox = tx * TW;

    const float* xb = x + (size_t)b * DIMC * PLANE;

    // ---------- Stage 0: x halo -> LDS f16 pairs, word = px*32 + (w ^ SWZ(px)) ----------
    // quad tasks (576): T = cg*144 + r*8 + q  (q fastest -> full-line coalescing)
    {
        auto quad = [&](int T) {
            const int cg = T / 144;
            const int rm = T - cg * 144;
            const int r  = rm >> 3;
            const int q  = rm & 7;
            const int gy = oy + r - 1;
            const int p0 = r * HW + 1 + 4 * q;
            if ((unsigned)gy >= IMH) {
                #pragma unroll
                for (int j = 0; j < 4; ++j) {
                    const uint p = (uint)(p0 + j), base = p << 5, sw = SWZ(p);
                    uint4 z = {0u, 0u, 0u, 0u};
                    *reinterpret_cast<uint4*>(&ts[base + (((uint)(cg*8))   ^ sw)]) = z;
                    *reinterpret_cast<uint4*>(&ts[base + (((uint)(cg*8+4)) ^ sw)]) = z;
                }
            } else {
                const float* xp = xb + (size_t)(cg*16) * PLANE + (size_t)gy * IMW + (ox + 4*q);
                f32x4 f[16];
                #pragma unroll
                for (int i = 0; i < 16; ++i)
                    f[i] = *reinterpret_cast<const f32x4*>(xp + (size_t)i * PLANE);
                #pragma unroll
                for (int j = 0; j < 4; ++j) {
                    const uint p = (uint)(p0 + j), base = p << 5, sw = SWZ(p);
                    uint4 o0, o1;
                    o0.x = pkrtz(f[0][j],  f[1][j]);  o0.y = pkrtz(f[2][j],  f[3][j]);
                    o0.z = pkrtz(f[4][j],  f[5][j]);  o0.w = pkrtz(f[6][j],  f[7][j]);
                    o1.x = pkrtz(f[8][j],  f[9][j]);  o1.y = pkrtz(f[10][j], f[11][j]);
                    o1.z = pkrtz(f[12][j], f[13][j]); o1.w = pkrtz(f[14][j], f[15][j]);
                    *reinterpret_cast<uint4*>(&ts[base + (((uint)(cg*8))   ^ sw)]) = o0;
                    *reinterpret_cast<uint4*>(&ts[base + (((uint)(cg*8+4)) ^ sw)]) = o1;
                }
            }
        };
        // edge tasks (144): E = cg*36 + s*18 + r ; 1 px (gx = ox-1 or ox+32) x 16 ch
        auto edge = [&](int E) {
            const int cg = E / 36;
            const int rm = E - cg * 36;
            const int s  = rm / 18;
            const int r  = rm - s * 18;
            const int gy = oy + r - 1;
            const int gx = s ? (ox + TW) : (ox - 1);
            const uint p = (uint)(r * HW + (s ? 33 : 0));
            const uint base = p << 5, sw = SWZ(p);
            if ((unsigned)gy >= IMH || (unsigned)gx >= IMW) {
                uint4 z = {0u, 0u, 0u, 0u};
                *reinterpret_cast<uint4*>(&ts[base + (((uint)(cg*8))   ^ sw)]) = z;
                *reinterpret_cast<uint4*>(&ts[base + (((uint)(cg*8+4)) ^ sw)]) = z;
            } else {
                const float* xp = xb + (size_t)(cg*16) * PLANE + (size_t)gy * IMW + gx;
                float f[16];
                #pragma unroll
                for (int i = 0; i < 16; ++i) f[i] = xp[(size_t)i * PLANE];
                uint4 o0, o1;
                o0.x = pkrtz(f[0], f[1]);   o0.y = pkrtz(f[2], f[3]);
                o0.z = pkrtz(f[4], f[5]);   o0.w = pkrtz(f[6], f[7]);
                o1.x = pkrtz(f[8], f[9]);   o1.y = pkrtz(f[10], f[11]);
                o1.z = pkrtz(f[12], f[13]); o1.w = pkrtz(f[14], f[15]);
                *reinterpret_cast<uint4*>(&ts[base + (((uint)(cg*8))   ^ sw)]) = o0;
                *reinterpret_cast<uint4*>(&ts[base + (((uint)(cg*8+4)) ^ sw)]) = o1;
            }
        };
        quad(tid);
        if (tid < 64) quad(512 + tid);
        if (tid >= 368) edge(tid - 368);
        if (tid < 12) {   // zero pad px 612..623
            const uint p = (uint)(612 + tid);
            const uint base = p << 5, sw = SWZ(p);
            uint4 z = {0u, 0u, 0u, 0u};
            #pragma unroll
            for (int g = 0; g < 8; ++g)
                *reinterpret_cast<uint4*>(&ts[base + (((uint)(g << 2)) ^ sw)]) = z;
        }
    }

    const int lane = tid & 63, wid = tid >> 6;
    const int l15 = lane & 15, lg = lane >> 4;
    const int li = tid >> 5, lj = tid & 31;

    // ---------- A-fragments from pre-converted f16 weights ----------
    half8 afrag1[4][2];
    const uint4* w1v = reinterpret_cast<const uint4*>(ws + W1OFF);
    #pragma unroll
    for (int mt = 0; mt < 4; ++mt)
        #pragma unroll
        for (int ks = 0; ks < 2; ++ks) {
            U4H8 u; u.u = w1v[(mt*16 + l15)*8 + ks*4 + lg];
            afrag1[mt][ks] = u.h;
        }
    half8 afrag2[4];
    const uint4* w2v = reinterpret_cast<const uint4*>(ws + W2OFF);
    #pragma unroll
    for (int mt = 0; mt < 4; ++mt) { U4H8 u; u.u = w2v[(mt*16 + l15)*4 + lg]; afrag2[mt] = u.h; }

    const uint ident = ws[IDOFF];
    __syncthreads();

    // ---------- Snapshot shortcut x in store-side layout ----------
    uint xs[4][4][2];
    #pragma unroll
    for (int cc = 0; cc < 4; ++cc) {
        const int px = wid*64 + cc*16 + l15;
        const int h  = ((px >> 5) + 1) * HW + (px & 31) + 1;
        const uint base = (uint)h << 5, sw = SWZ(h);
        #pragma unroll
        for (int mt = 0; mt < 4; ++mt) {
            const uint a = base + (((uint)(mt*8 + lg*2)) ^ sw);
            xs[cc][mt][0] = ts[a];
            xs[cc][mt][1] = ts[a + 1];
        }
    }
    __syncthreads();

    // ---------- Stage A: t = W1 * x via MFMA f16, in-place (ch, ch+32) pairs ----------
    for (int chunk = wid; chunk < NCHUNK; chunk += 8) {
        const uint px = (uint)(chunk*16 + l15);
        const uint base = px << 5, sw = SWZ(px);
        f32x4 acc[4];
        #pragma unroll
        for (int mt = 0; mt < 4; ++mt) acc[mt] = (f32x4)0.0f;
        #pragma unroll
        for (int ks = 0; ks < 2; ++ks) {
            U4H8 u; u.u = *reinterpret_cast<const uint4*>(&ts[base + (((uint)(ks*16 + lg*4)) ^ sw)]);
            #pragma unroll
            for (int mt = 0; mt < 4; ++mt)
                acc[mt] = __builtin_amdgcn_mfma_f32_16x16x32_f16(afrag1[mt][ks], u.h, acc[mt], 0, 0, 0);
        }
        #pragma unroll
        for (int mt = 0; mt < 2; ++mt) {
            uint4 o;
            o.x = pkrtz(acc[mt][0], acc[mt+2][0]);
            o.y = pkrtz(acc[mt][1], acc[mt+2][1]);
            o.z = pkrtz(acc[mt][2], acc[mt+2][2]);
            o.w = pkrtz(acc[mt][3], acc[mt+2][3]);
            *reinterpret_cast<uint4*>(&ts[base + (((uint)(mt*16 + lg*4)) ^ sw)]) = o;
        }
    }
    __syncthreads();

    // ---------- Stage B: depthwise 3x3 via v_pk_fma_f16, SGPR weights ----------
    uint acc2[32];
    #pragma unroll
    for (int c = 0; c < 32; ++c) acc2[c] = 0u;
    #pragma unroll
    for (int k = 0; k < 9; ++k) {
        const int di = k / 3, dj = k - di * 3;
        const uint hpx = (uint)((li + di) * HW + (lj + dj));
        const uint base = hpx << 5, sw = SWZ(hpx);
        const uint4* pwv = reinterpret_cast<const uint4*>(ws + PWOFF + k*32);  // uniform -> s_load
        #pragma unroll
        for (int g = 0; g < 8; ++g) {
            const uint4 wv = pwv[g];
            const uint4 tv = *reinterpret_cast<const uint4*>(&ts[base + (((uint)(g << 2)) ^ sw)]);
            acc2[g*4+0] = pkfma(wv.x, tv.x, acc2[g*4+0]);
            acc2[g*4+1] = pkfma(wv.y, tv.y, acc2[g*4+1]);
            acc2[g*4+2] = pkfma(wv.z, tv.z, acc2[g*4+2]);
            acc2[g*4+3] = pkfma(wv.w, tv.w, acc2[g*4+3]);
        }
    }
    // GELU gate -> packed v (16 words)
    uint4 vo[4];
    #pragma unroll
    for (int gg = 0; gg < 4; ++gg) {
        uint o[4];
        #pragma unroll
        for (int q = 0; q < 4; ++q) {
            const int c2 = gg*4 + q;
            const uint wa = acc2[2*c2], wb = acc2[2*c2 + 1];
            const float v0 = gelu_f(lo16f(wa)) * hi16f(wa);
            const float v1 = gelu_f(lo16f(wb)) * hi16f(wb);
            o[q] = pkrtz(v0, v1);
        }
        vo[gg].x = o[0]; vo[gg].y = o[1]; vo[gg].z = o[2]; vo[gg].w = o[3];
    }
    __syncthreads();   // all t reads complete before v overwrites
    {
        const uint vb = (uint)tid * VSTR;
        #pragma unroll
        for (int gg = 0; gg < 4; ++gg)
            *reinterpret_cast<uint4*>(&ts[vb + (uint)(gg << 2)]) = vo[gg];
    }
    __syncthreads();

    // ---------- Stage D: y = W2 * v via MFMA; add f16 shortcut from regs; store ----------
    float* ob = out + (size_t)b * DIMC * PLANE;
    if (ident) {
        #pragma unroll
        for (int cc = 0; cc < 4; ++cc) {
            const uint px = (uint)(wid*64 + cc*16 + l15);
            U4H8 u; u.u = *reinterpret_cast<const uint4*>(&ts[px * VSTR + (uint)(lg << 2)]);
            const size_t pix = (size_t)(oy + (int)(px >> 5)) * IMW + (ox + (int)(px & 31));
            float* op = ob + pix;
            #pragma unroll
            for (int mt = 0; mt < 4; ++mt) {
                f32x4 a = __builtin_amdgcn_mfma_f32_16x16x32_f16(afrag2[mt], u.h, (f32x4)0.0f, 0, 0, 0);
                #pragma unroll
                for (int r = 0; r < 4; ++r) {
                    const int ch = mt*16 + lg*4 + r;
                    const uint xw = xs[cc][mt][r >> 1];
                    const float xv = (r & 1) ? hi16f(xw) : lo16f(xw);
                    op[(size_t)ch * PLANE] = a[r] + xv;
                }
            }
        }
    } else {
        // general path (not hit in bench): 4 passes of 16 channels; ys after v region
        float* ys = reinterpret_cast<float*>(ts + 10240);   // [16][520] floats = 8320 words
        for (int mt = 0; mt < 4; ++mt) {
            __syncthreads();
            #pragma unroll
            for (int cc = 0; cc < 4; ++cc) {
                const uint px = (uint)(wid*64 + cc*16 + l15);
                U4H8 u; u.u = *reinterpret_cast<const uint4*>(&ts[px * VSTR + (uint)(lg << 2)]);
                f32x4 a = __builtin_amdgcn_mfma_f32_16x16x32_f16(afrag2[mt], u.h, (f32x4)0.0f, 0, 0, 0);
                #pragma unroll
                for (int r = 0; r < 4; ++r)
                    ys[(lg*4 + r) * 520 + (int)px] = a[r];
            }
            __syncthreads();
            {
                const int chl = tid >> 5;
                const int ch  = mt*16 + chl;
                const int pt  = tid & 31;
                const int pi = (pt >> 3) * 4, pj = (pt & 7) * 4;
                float yv[4][4];
                #pragma unroll
                for (int a = 0; a < 4; ++a)
                    #pragma unroll
                    for (int c = 0; c < 4; ++c)
                        yv[a][c] = ys[chl * 520 + (pi + a) * TW + (pj + c)];
                float Cr[4][4], Ci[4][4];
                #pragma unroll
                for (int j = 0; j < 4; ++j) {
                    const float s02 = yv[0][j] + yv[2][j], d02 = yv[0][j] - yv[2][j];
                    const float s13 = yv[1][j] + yv[3][j], d13 = yv[1][j] - yv[3][j];
                    Cr[0][j] = s02 + s13; Ci[0][j] = 0.0f;
                    Cr[1][j] = d02;       Ci[1][j] = -d13;
                    Cr[2][j] = s02 - s13; Ci[2][j] = 0.0f;
                    Cr[3][j] = d02;       Ci[3][j] = d13;
                }
                float Zr[4][3], Zi[4][3];
                #pragma unroll
                for (int u = 0; u < 4; ++u) {
                    const float r0 = Cr[u][0], r1 = Cr[u][1], r2 = Cr[u][2], r3 = Cr[u][3];
                    const float i0 = Ci[u][0], i1 = Ci[u][1], i2 = Ci[u][2], i3 = Ci[u][3];
                    Zr[u][0] = r0 + r1 + r2 + r3;     Zi[u][0] = i0 + i1 + i2 + i3;
                    Zr[u][1] = (r0 - r2) + (i1 - i3); Zi[u][1] = (i0 - i2) - (r1 - r3);
                    Zr[u][2] = r0 - r1 + r2 - r3;     Zi[u][2] = i0 - i1 + i2 - i3;
                    #pragma unroll
                    for (int vv = 0; vv < 3; ++vv) {
                        const float m = wf[ch * 12 + u * 3 + vv];
                        Zr[u][vv] *= m; Zi[u][vv] *= m;
                    }
                }
                float Ar[4][3], Ai[4][3];
                #pragma unroll
                for (int vv = 0; vv < 3; ++vv) {
                    const float r0 = Zr[0][vv], r1 = Zr[1][vv], r2 = Zr[2][vv], r3 = Zr[3][vv];
                    const float i0 = Zi[0][vv], i1 = Zi[1][vv], i2 = Zi[2][vv], i3 = Zi[3][vv];
                    Ar[0][vv] = r0 + r1 + r2 + r3;     Ai[0][vv] = i0 + i1 + i2 + i3;
                    Ar[1][vv] = (r0 - r2) - (i1 - i3); Ai[1][vv] = (i0 - i2) + (r1 - r3);
                    Ar[2][vv] = r0 - r1 + r2 - r3;     Ai[2][vv] = i0 - i1 + i2 - i3;
                    Ar[3][vv] = (r0 - r2) + (i1 - i3); Ai[3][vv] = (i0 - i2) - (r1 - r3);
                }
                const float* xc = xb + (size_t)ch * PLANE;
                float*       oc = ob + (size_t)ch * PLANE;
                #pragma unroll
                for (int a = 0; a < 4; ++a) {
                    const float A0 = Ar[a][0], A1r = Ar[a][1], A2 = Ar[a][2];
                    const float B1i = Ai[a][1];
                    float res[4];
                    res[0] = (A0 + 2.0f * A1r + A2) * 0.0625f;
                    res[1] = (A0 - 2.0f * B1i - A2) * 0.0625f;
                    res[2] = (A0 - 2.0f * A1r + A2) * 0.0625f;
                    res[3] = (A0 + 2.0f * B1i - A2) * 0.0625f;
                    #pragma unroll
                    for (int c = 0; c < 4; ++c) {
                        const size_t pix = (size_t)(oy + pi + a) * IMW + (ox + pj + c);
                        oc[pix] = res[c] + xc[pix];
                    }
                }
            }
        }
    }
}

extern "C" void kernel_launch(void* const* d_in, const int* in_sizes, int n_in,
                              void* d_out, int out_size, void* d_ws, size_t ws_size,
                              hipStream_t stream) {
    (void)in_sizes; (void)n_in; (void)ws_size; (void)out_size;
    const float* x   = (const float*)d_in[0];
    const float* w1  = (const float*)d_in[1];
    const float* wdw = (const float*)d_in[2];
    const float* w2  = (const float*)d_in[3];
    const float* wf  = (const float*)d_in[4];
    float* out = (float*)d_out;
    uint* ws = (uint*)d_ws;

    ffn_prep<<<1, 256, 0, stream>>>(w1, wdw, w2, wf, ws);
    const int blocks = 4 * (IMH / TH) * (IMW / TW);   // 2048
    ffn_main<<<blocks, 512, 0, stream>>>(x, ws, wf, out);
}